// Round 3
// baseline (1275.684 us; speedup 1.0000x reference)
//
#include <hip/hip_runtime.h>
#include <hip/hip_fp16.h>

#define D 128
#define N_ITER 20
#define HBITS 15                  // col-degree histogram: 32768 nodes per range
#define HWORDS (1 << (HBITS - 1)) // 16384 packed uint16-pair words = 64 KB LDS
#define HB2 14                    // placement ranges: 16384 nodes, u32 (cm|cu<<16) each
#define HW2 (1 << HB2)            // 16384 words = 64 KB LDS

// ---------------- mask dtype detection (sampled prefix is sufficient) ----------------
__global__ void k_detect(const unsigned char* __restrict__ m, int nbytes, int* flag) {
    __shared__ int s;
    if (threadIdx.x == 0) s = 0;
    __syncthreads();
    int c = 0;
    for (int i = threadIdx.x; i < nbytes; i += 256)
        if ((i & 3) && m[i]) c++;
    atomicAdd(&s, c);
    __syncthreads();
    if (threadIdx.x == 0) *flag = (s > 0) ? 1 : 0;
}

__global__ void k_mask(const void* __restrict__ mraw, const int* __restrict__ flag,
                       unsigned char* __restrict__ m8, int* __restrict__ nm, int n) {
    int i = blockIdx.x * 256 + threadIdx.x;
    if (i >= n) return;
    unsigned char v;
    if (*flag) {
        v = ((const unsigned char*)mraw)[i] != 0;
    } else {
        v = ((const int*)mraw)[i] != 0;
    }
    m8[i] = v;
    nm[i] = v ? 0 : 1;
}

// ---------------- col-degree histogram (for dis): LDS-privatized, packed u16 ---------
__global__ __launch_bounds__(256) void k_hist(const int* __restrict__ keys, int E,
                                              int Bp, int per,
                                              unsigned int* __restrict__ sc) {
    __shared__ unsigned int h[HWORDS];
    int r = blockIdx.x / Bp;
    int b = blockIdx.x - r * Bp;
    for (int i = threadIdx.x; i < HWORDS; i += 256) h[i] = 0;
    __syncthreads();
    int lo = r << HBITS;
    int beg = b * per;
    int end = min(beg + per, E);
    int e = beg + (threadIdx.x << 2);
    for (; e + 3 < end; e += 1024) {
        int4 k4 = *(const int4*)(keys + e);
        int k;
        k = k4.x - lo; if ((unsigned)k < (unsigned)(1 << HBITS)) atomicAdd(&h[k >> 1], 1u << ((k & 1) << 4));
        k = k4.y - lo; if ((unsigned)k < (unsigned)(1 << HBITS)) atomicAdd(&h[k >> 1], 1u << ((k & 1) << 4));
        k = k4.z - lo; if ((unsigned)k < (unsigned)(1 << HBITS)) atomicAdd(&h[k >> 1], 1u << ((k & 1) << 4));
        k = k4.w - lo; if ((unsigned)k < (unsigned)(1 << HBITS)) atomicAdd(&h[k >> 1], 1u << ((k & 1) << 4));
    }
    for (int ee = e; ee < end && ee < e + 4; ee++) {
        int k = keys[ee] - lo;
        if ((unsigned)k < (unsigned)(1 << HBITS)) atomicAdd(&h[k >> 1], 1u << ((k & 1) << 4));
    }
    __syncthreads();
    unsigned int* out = sc + ((size_t)blockIdx.x << (HBITS - 1));
    for (int i = threadIdx.x; i < HWORDS; i += 256) out[i] = h[i];
}

// ---------------- reduce col histograms -> dis ----------------
__global__ void k_red(const unsigned int* __restrict__ sc, int Bp,
                      float* __restrict__ dis, int N, int R) {
    int w = blockIdx.x * 256 + threadIdx.x;
    if (w >= (R << (HBITS - 1))) return;
    int r = w >> (HBITS - 1);
    int word = w & (HWORDS - 1);
    int n0 = (r << HBITS) + (word << 1);
    if (n0 >= N) return;
    const unsigned int* p = sc + (((size_t)r * Bp) << (HBITS - 1)) + word;
    unsigned int slo = 0, shi = 0;
    for (int b = 0; b < Bp; b++) {
        unsigned int v = p[(size_t)b << (HBITS - 1)];
        slo += v & 0xffffu;
        shi += v >> 16;
    }
    dis[n0] = slo ? rsqrtf((float)slo) : 0.f;
    if (n0 + 1 < N) dis[n0 + 1] = shi ? rsqrtf((float)shi) : 0.f;
}

// ---------------- placement pass 1: per-(range,slice) counts, cm|cu<<16 per node -----
__global__ __launch_bounds__(256) void k_cnt(const int* __restrict__ row,
                                             const int* __restrict__ col, int E,
                                             const unsigned char* __restrict__ m8,
                                             int Bp, int per,
                                             unsigned int* __restrict__ sc) {
    __shared__ unsigned int h[HW2];
    int r = blockIdx.x / Bp;
    int b = blockIdx.x - r * Bp;
    for (int i = threadIdx.x; i < HW2; i += 256) h[i] = 0;
    __syncthreads();
    int lo = r << HB2;
    int beg = b * per;
    int end = min(beg + per, E);
    int e = beg + (threadIdx.x << 2);
    for (; e + 3 < end; e += 1024) {
        int4 r4 = *(const int4*)(row + e);
        int4 c4 = *(const int4*)(col + e);
        int k;
        k = r4.x - lo; if ((unsigned)k < (unsigned)HW2 && !m8[r4.x]) atomicAdd(&h[k], m8[c4.x] ? 1u : 65536u);
        k = r4.y - lo; if ((unsigned)k < (unsigned)HW2 && !m8[r4.y]) atomicAdd(&h[k], m8[c4.y] ? 1u : 65536u);
        k = r4.z - lo; if ((unsigned)k < (unsigned)HW2 && !m8[r4.z]) atomicAdd(&h[k], m8[c4.z] ? 1u : 65536u);
        k = r4.w - lo; if ((unsigned)k < (unsigned)HW2 && !m8[r4.w]) atomicAdd(&h[k], m8[c4.w] ? 1u : 65536u);
    }
    for (int ee = e; ee < end && ee < e + 4; ee++) {
        int rr = row[ee];
        int k = rr - lo;
        if ((unsigned)k < (unsigned)HW2 && !m8[rr]) atomicAdd(&h[k], m8[col[ee]] ? 1u : 65536u);
    }
    __syncthreads();
    unsigned int* out = sc + ((size_t)blockIdx.x << HB2);
    for (int i = threadIdx.x; i < HW2; i += 256) out[i] = h[i];
}

// ---------------- placement pass 2: counts -> exclusive prefixes; emit rdeg, cmtot ----
__global__ void k_pfx(unsigned int* __restrict__ sc, int Bp, int N,
                      int* __restrict__ rdeg, int* __restrict__ cmtot) {
    int w = blockIdx.x * 256 + threadIdx.x;   // (range, node-in-range)
    int r = w >> HB2;
    int n = w & (HW2 - 1);
    int node = (r << HB2) + n;
    if (node >= N) return;
    unsigned int* p = sc + (((size_t)r * Bp) << HB2) + n;
    unsigned int cm = 0, cu = 0;
    for (int b = 0; b < Bp; b++) {
        unsigned int v = p[(size_t)b << HB2];
        p[(size_t)b << HB2] = cm | (cu << 16);
        cm += v & 0xffffu;
        cu += v >> 16;
    }
    rdeg[node] = (int)(cm + cu);
    cmtot[node] = (int)cm;
}

// ---------------- placement pass 3: deterministic scatter, LDS-rank only -------------
__global__ __launch_bounds__(256) void k_place(const int* __restrict__ row,
                                               const int* __restrict__ col, int E,
                                               const unsigned char* __restrict__ m8,
                                               int Bp, int per,
                                               const unsigned int* __restrict__ sc,
                                               const int* __restrict__ base_m,
                                               const int* __restrict__ base_u,
                                               int* __restrict__ col_s) {
    __shared__ unsigned int h[HW2];
    int r = blockIdx.x / Bp;
    int b = blockIdx.x - r * Bp;
    const unsigned int* in = sc + ((size_t)blockIdx.x << HB2);
    for (int i = threadIdx.x; i < HW2; i += 256) h[i] = in[i];
    __syncthreads();
    int lo = r << HB2;
    int beg = b * per;
    int end = min(beg + per, E);
    int e = beg + (threadIdx.x << 2);
    for (; e + 3 < end; e += 1024) {
        int4 r4 = *(const int4*)(row + e);
        int4 c4 = *(const int4*)(col + e);
#pragma unroll
        for (int j = 0; j < 4; j++) {
            int rr = j == 0 ? r4.x : j == 1 ? r4.y : j == 2 ? r4.z : r4.w;
            int cc = j == 0 ? c4.x : j == 1 ? c4.y : j == 2 ? c4.z : c4.w;
            int k = rr - lo;
            if ((unsigned)k < (unsigned)HW2 && !m8[rr]) {
                int p;
                if (m8[cc]) {
                    unsigned int old = atomicAdd(&h[k], 1u);
                    p = base_m[rr] + (int)(old & 0xffffu);
                } else {
                    unsigned int old = atomicAdd(&h[k], 65536u);
                    p = base_u[rr] + (int)(old >> 16);
                }
                col_s[p] = cc;
            }
        }
    }
    for (int ee = e; ee < end && ee < e + 4; ee++) {
        int rr = row[ee];
        int k = rr - lo;
        if ((unsigned)k < (unsigned)HW2 && !m8[rr]) {
            int cc = col[ee];
            int p;
            if (m8[cc]) {
                unsigned int old = atomicAdd(&h[k], 1u);
                p = base_m[rr] + (int)(old & 0xffffu);
            } else {
                unsigned int old = atomicAdd(&h[k], 65536u);
                p = base_u[rr] + (int)(old >> 16);
            }
            col_s[p] = cc;
        }
    }
}

// ---------------- exclusive scan (generic over input array) ----------------
__global__ void k_scan1(const int* __restrict__ a, int* __restrict__ csum, int n) {
    __shared__ int sh[256];
    int base = blockIdx.x * 2048;
    int t = threadIdx.x;
    int s = 0;
    for (int j = 0; j < 8; j++) {
        int i = base + t * 8 + j;
        if (i < n) s += a[i];
    }
    sh[t] = s;
    __syncthreads();
    for (int o = 128; o > 0; o >>= 1) {
        if (t < o) sh[t] += sh[t + o];
        __syncthreads();
    }
    if (t == 0) csum[blockIdx.x] = sh[0];
}

__global__ void k_scan2(int* __restrict__ csum, int nch, int* __restrict__ out_off, int n) {
    if (threadIdx.x == 0) {
        int acc = 0;
        for (int i = 0; i < nch; i++) { int v = csum[i]; csum[i] = acc; acc += v; }
        out_off[n] = acc;
    }
}

__global__ void k_scan3(const int* __restrict__ a, const int* __restrict__ csum,
                        int* __restrict__ out_off, int n) {
    __shared__ int sh[256];
    int base = blockIdx.x * 2048;
    int t = threadIdx.x;
    int loc[8];
    int s = 0;
    for (int j = 0; j < 8; j++) {
        int i = base + t * 8 + j;
        int v = (i < n) ? a[i] : 0;
        loc[j] = s;
        s += v;
    }
    sh[t] = s;
    __syncthreads();
    for (int o = 1; o < 256; o <<= 1) {
        int v = (t >= o) ? sh[t - o] : 0;
        __syncthreads();
        sh[t] += v;
        __syncthreads();
    }
    int toff = csum[blockIdx.x] + ((t > 0) ? sh[t - 1] : 0);
    for (int j = 0; j < 8; j++) {
        int i = base + t * 8 + j;
        if (i < n) out_off[i] = toff + loc[j];
    }
}

// ---------------- ordered compact: rows_c[cpos[i]] = i for unmasked i ----------------
__global__ void k_fill(const unsigned char* __restrict__ m8, const int* __restrict__ cpos,
                       int* __restrict__ rows_c, int n) {
    int i = blockIdx.x * 256 + threadIdx.x;
    if (i >= n) return;
    if (!m8[i]) rows_c[cpos[i]] = i;
}

// ---------------- per-row descriptors + placement bases ----------------
__global__ void k_desc(const int* __restrict__ rows_c, const int* __restrict__ cnt_p,
                       const int* __restrict__ row_off, const int* __restrict__ cmtot,
                       int4* __restrict__ di, int4* __restrict__ dsx,
                       int* __restrict__ base_m, int* __restrict__ base_u) {
    int i = blockIdx.x * 256 + threadIdx.x;
    if (i >= *cnt_p) return;
    int r = rows_c[i];
    int ro = row_off[r];
    int cm = cmtot[r];
    int ro1 = row_off[r + 1];
    di[i]  = make_int4(r, ro + cm, ro1, 0);   // unmasked-col edge range (per-iteration gather)
    dsx[i] = make_int4(r, ro, ro + cm, 0);    // masked-col edge range (S_fix)
    base_m[r] = ro;
    base_u[r] = ro + cm;
}

// ---------------- init: masked rows of d_out = x ----------------
__global__ void k_init(const float* __restrict__ x, const unsigned char* __restrict__ m8,
                       float* __restrict__ out, int nvec) {
    int i = blockIdx.x * 256 + threadIdx.x;  // float4 index, 32 per node
    if (i >= nvec) return;
    int node = i >> 5;
    if (m8[node]) ((float4*)out)[i] = ((const float4*)x)[i];
}

// ---------------- S_fix[r] = sum over masked cols of dis[c]*x[c]  (fp16 store) -------
// Also writes u1[r] = dis[r]^2 * S_fix[r].
__global__ __launch_bounds__(256) void k_sfix(const float* __restrict__ x,
                                              const float* __restrict__ dis,
                                              const int4* __restrict__ desc,
                                              const int* __restrict__ cnt_p,
                                              const int* __restrict__ col_s,
                                              uint2* __restrict__ S,
                                              uint2* __restrict__ u1) {
    int wgid = (blockIdx.x * 256 + threadIdx.x) >> 6;
    int lane = threadIdx.x & 63;
    int nw = gridDim.x << 2;
    int cn = *cnt_p;

    int s = lane >> 5;     // edge slot 0..1
    int f = lane & 31;     // float4 slot within 512B row
    const float4* xb = (const float4*)x + f;

    for (int wid = wgid; wid < cn; wid += nw) {
        int4 dsc = desc[wid];
        int r   = __builtin_amdgcn_readfirstlane(dsc.x);
        int beg = __builtin_amdgcn_readfirstlane(dsc.y);
        int end = __builtin_amdgcn_readfirstlane(dsc.z);

        float a0 = 0, a1 = 0, a2 = 0, a3 = 0;
        float b0 = 0, b1 = 0, b2 = 0, b3 = 0;
        int e = beg;
        for (; e + 8 <= end; e += 8) {
            int c0 = col_s[e + s],     c1 = col_s[e + 2 + s];
            int c2 = col_s[e + 4 + s], c3 = col_s[e + 6 + s];
            float w0 = dis[c0], w1 = dis[c1], w2 = dis[c2], w3 = dis[c3];
            float4 v0 = xb[(size_t)c0 * 32];
            float4 v1 = xb[(size_t)c1 * 32];
            float4 v2 = xb[(size_t)c2 * 32];
            float4 v3 = xb[(size_t)c3 * 32];
            a0 += w0 * v0.x; a1 += w0 * v0.y; a2 += w0 * v0.z; a3 += w0 * v0.w;
            b0 += w1 * v1.x; b1 += w1 * v1.y; b2 += w1 * v1.z; b3 += w1 * v1.w;
            a0 += w2 * v2.x; a1 += w2 * v2.y; a2 += w2 * v2.z; a3 += w2 * v2.w;
            b0 += w3 * v3.x; b1 += w3 * v3.y; b2 += w3 * v3.z; b3 += w3 * v3.w;
        }
        for (; e + 2 <= end; e += 2) {
            int c = col_s[e + s];
            float w = dis[c];
            float4 v = xb[(size_t)c * 32];
            a0 += w * v.x; a1 += w * v.y; a2 += w * v.z; a3 += w * v.w;
        }
        if (e < end && s == 0) {
            int c = col_s[e];
            float w = dis[c];
            float4 v = xb[(size_t)c * 32];
            a0 += w * v.x; a1 += w * v.y; a2 += w * v.z; a3 += w * v.w;
        }
        a0 += b0; a1 += b1; a2 += b2; a3 += b3;
        a0 += __shfl_xor(a0, 32, 64);
        a1 += __shfl_xor(a1, 32, 64);
        a2 += __shfl_xor(a2, 32, 64);
        a3 += __shfl_xor(a3, 32, 64);
        if (lane < 32) {
            __half2 h0 = __floats2half2_rn(a0, a1);
            __half2 h1 = __floats2half2_rn(a2, a3);
            uint2 o;
            __builtin_memcpy(&o.x, &h0, 4);
            __builtin_memcpy(&o.y, &h1, 4);
            S[(size_t)r * 32 + f] = o;
            float dd = dis[r];
            float ss = dd * dd;
            __half2 g0 = __floats2half2_rn(ss * a0, ss * a1);
            __half2 g1 = __floats2half2_rn(ss * a2, ss * a3);
            uint2 o2;
            __builtin_memcpy(&o2.x, &g0, 4);
            __builtin_memcpy(&o2.y, &g1, 4);
            u1[(size_t)r * 32 + f] = o2;
        }
    }
}

// ---------------- iteration: gather unmasked-col edges, acc starts at S_fix ----------
template <bool FINAL>
__global__ __launch_bounds__(256) void k_iter(const uint2* __restrict__ src,
                                              void* __restrict__ dst,
                                              const uint2* __restrict__ S,
                                              const int4* __restrict__ desc,
                                              const int* __restrict__ cnt_p,
                                              const int* __restrict__ col_s,
                                              const float* __restrict__ dis) {
    int wgid = (blockIdx.x * 256 + threadIdx.x) >> 6;
    int lane = threadIdx.x & 63;
    int nw = gridDim.x << 2;
    int cn = *cnt_p;

    int s = lane >> 5;     // edge slot 0..1
    int f = lane & 31;     // uint2 (half4) slot, row stride 32
    const uint2* cb = src + f;

    for (int wid = wgid; wid < cn; wid += nw) {
        int4 dsc = desc[wid];
        int r   = __builtin_amdgcn_readfirstlane(dsc.x);
        int beg = __builtin_amdgcn_readfirstlane(dsc.y);
        int end = __builtin_amdgcn_readfirstlane(dsc.z);

        float a0, a1, a2, a3;
        if (s == 0) {
            uint2 sv = S[(size_t)r * 32 + f];
            __half2 h0, h1;
            __builtin_memcpy(&h0, &sv.x, 4);
            __builtin_memcpy(&h1, &sv.y, 4);
            float2 v0 = __half22float2(h0);
            float2 v1 = __half22float2(h1);
            a0 = v0.x; a1 = v0.y; a2 = v1.x; a3 = v1.y;
        } else {
            a0 = a1 = a2 = a3 = 0.f;
        }
        float b0 = 0.f, b1 = 0.f, b2 = 0.f, b3 = 0.f;

        int e = beg;
        for (; e + 16 <= end; e += 16) {
            int c[8];
#pragma unroll
            for (int j = 0; j < 8; j++) c[j] = col_s[e + 2 * j + s];
            uint2 g[8];
#pragma unroll
            for (int j = 0; j < 8; j++) g[j] = cb[(size_t)c[j] * 32];
#pragma unroll
            for (int j = 0; j < 8; j++) {
                __half2 hlo, hhi;
                __builtin_memcpy(&hlo, &g[j].x, 4);
                __builtin_memcpy(&hhi, &g[j].y, 4);
                float2 vlo = __half22float2(hlo);
                float2 vhi = __half22float2(hhi);
                if (j & 1) { b0 += vlo.x; b1 += vlo.y; b2 += vhi.x; b3 += vhi.y; }
                else       { a0 += vlo.x; a1 += vlo.y; a2 += vhi.x; a3 += vhi.y; }
            }
        }
        for (; e + 2 <= end; e += 2) {
            int c = col_s[e + s];
            uint2 g = cb[(size_t)c * 32];
            __half2 hlo, hhi;
            __builtin_memcpy(&hlo, &g.x, 4);
            __builtin_memcpy(&hhi, &g.y, 4);
            float2 vlo = __half22float2(hlo);
            float2 vhi = __half22float2(hhi);
            a0 += vlo.x; a1 += vlo.y; a2 += vhi.x; a3 += vhi.y;
        }
        if (e < end && s == 0) {
            int c = col_s[e];
            uint2 g = cb[(size_t)c * 32];
            __half2 hlo, hhi;
            __builtin_memcpy(&hlo, &g.x, 4);
            __builtin_memcpy(&hhi, &g.y, 4);
            float2 vlo = __half22float2(hlo);
            float2 vhi = __half22float2(hhi);
            a0 += vlo.x; a1 += vlo.y; a2 += vhi.x; a3 += vhi.y;
        }
        a0 += b0; a1 += b1; a2 += b2; a3 += b3;
        a0 += __shfl_xor(a0, 32, 64);
        a1 += __shfl_xor(a1, 32, 64);
        a2 += __shfl_xor(a2, 32, 64);
        a3 += __shfl_xor(a3, 32, 64);

        if (lane < 32) {
            float d = dis[r];
            if (FINAL) {
                ((float4*)dst)[(size_t)r * 32 + f] = make_float4(d * a0, d * a1, d * a2, d * a3);
            } else {
                float ss = d * d;
                __half2 h0 = __floats2half2_rn(ss * a0, ss * a1);
                __half2 h1 = __floats2half2_rn(ss * a2, ss * a3);
                uint2 o;
                __builtin_memcpy(&o.x, &h0, 4);
                __builtin_memcpy(&o.y, &h1, 4);
                ((uint2*)dst)[(size_t)r * 32 + f] = o;
            }
        }
    }
}

extern "C" void kernel_launch(void* const* d_in, const int* in_sizes, int n_in,
                              void* d_out, int out_size, void* d_ws, size_t ws_size,
                              hipStream_t stream) {
    const float* x = (const float*)d_in[0];
    const int* ei = (const int*)d_in[1];
    const void* mraw = d_in[2];

    const int N = in_sizes[0] / D;     // 100000
    const int E = in_sizes[1] / 2;     // 3200000
    const int* row = ei;
    const int* col = ei + E;

    char* ws = (char*)d_ws;
    size_t off = 0;
    uint2* uA = (uint2*)(ws + off);         off += (size_t)N * D * 2;   // fp16 u buffers
    uint2* uB = (uint2*)(ws + off);         off += (size_t)N * D * 2;
    uint2* S  = (uint2*)(ws + off);         off += (size_t)N * D * 2;   // fp16 S_fix
    int* col_s = (int*)(ws + off);          off += (size_t)E * 4;       // CSR cols (filtered, split)
    int* row_off = (int*)(ws + off);        off += (size_t)(N + 1) * 4;
    int* rdeg = (int*)(ws + off);           off += (size_t)N * 4;
    int* cmtot = (int*)(ws + off);          off += (size_t)N * 4;
    int* base_m = (int*)(ws + off);         off += (size_t)N * 4;
    int* base_u = (int*)(ws + off);         off += (size_t)N * 4;
    float* dis = (float*)(ws + off);        off += (size_t)N * 4;
    int* rows_c = (int*)(ws + off);         off += (size_t)N * 4;
    int* nm = (int*)(ws + off);             off += (size_t)N * 4;
    int* cpos = (int*)(ws + off);           off += (size_t)(N + 1) * 4;
    unsigned char* m8 = (unsigned char*)(ws + off); off += (size_t)N;
    off = (off + 255) & ~(size_t)255;
    int* csum = (int*)(ws + off);           off += 256 * 4;
    int* csum2 = (int*)(ws + off);          off += 256 * 4;
    int* flag = (int*)(ws + off);           off += 4;
    off = (off + 255) & ~(size_t)255;
    int4* desc_i = (int4*)(ws + off);       off += (size_t)N * 16;
    int4* desc_s = (int4*)(ws + off);       off += (size_t)N * 16;

    const int* cnt_p = cpos + N;   // total unmasked count, written by scan

    // histogram/placement scratch: aliases uA+uB (written only later by k_sfix/k_iter)
    unsigned int* sc = (unsigned int*)ws;

    int nb = N < 16384 ? N : 16384;
    k_detect<<<1, 256, 0, stream>>>((const unsigned char*)mraw, nb, flag);
    k_mask<<<(N + 255) / 256, 256, 0, stream>>>(mraw, flag, m8, nm, N);

    // col-degree histogram -> dis
    const int R = (N + (1 << HBITS) - 1) >> HBITS;   // 4 ranges of 32768
    const int Bp = 128;                              // slice <= 25008 < 65536
    int per = ((E + Bp - 1) / Bp + 15) & ~15;
    int rwords = (R << (HBITS - 1));
    k_hist<<<R * Bp, 256, 0, stream>>>(col, E, Bp, per, sc);
    k_red<<<(rwords + 255) / 256, 256, 0, stream>>>(sc, Bp, dis, N, R);

    // placement pass 1+2: per-(range,slice) split counts -> exclusive prefixes
    const int R2 = (N + HW2 - 1) >> HB2;             // 7 ranges of 16384
    const int Bp2 = 73;                              // ~511 blocks total
    int per2 = (((E + Bp2 - 1) / Bp2) + 3) & ~3;
    k_cnt<<<R2 * Bp2, 256, 0, stream>>>(row, col, E, m8, Bp2, per2, sc);
    k_pfx<<<(R2 << HB2) / 256, 256, 0, stream>>>(sc, Bp2, N, rdeg, cmtot);

    int nch = (N + 2047) / 2048;
    // scan rdeg -> row_off
    k_scan1<<<nch, 256, 0, stream>>>(rdeg, csum, N);
    k_scan2<<<1, 64, 0, stream>>>(csum, nch, row_off, N);
    k_scan3<<<nch, 256, 0, stream>>>(rdeg, csum, row_off, N);
    // scan !mask -> cpos (ordered compaction positions), cpos[N] = cnt
    k_scan1<<<nch, 256, 0, stream>>>(nm, csum2, N);
    k_scan2<<<1, 64, 0, stream>>>(csum2, nch, cpos, N);
    k_scan3<<<nch, 256, 0, stream>>>(nm, csum2, cpos, N);
    k_fill<<<(N + 255) / 256, 256, 0, stream>>>(m8, cpos, rows_c, N);

    k_desc<<<(N + 255) / 256, 256, 0, stream>>>(rows_c, cnt_p, row_off, cmtot,
                                                desc_i, desc_s, base_m, base_u);

    // placement pass 3: deterministic scatter with LDS ranks (no global atomics)
    k_place<<<R2 * Bp2, 256, 0, stream>>>(row, col, E, m8, Bp2, per2, sc,
                                          base_m, base_u, col_s);

    int nvec = N * (D / 4);
    k_init<<<(nvec + 255) / 256, 256, 0, stream>>>(x, m8, (float*)d_out, nvec);

    const int PBLK = 2048;   // persistent grid: 8192 waves, grid-stride over compact rows
    k_sfix<<<PBLK, 256, 0, stream>>>(x, dis, desc_s, cnt_p, col_s, S, uA);

    // u1 in uA; 18 fp16 gather iterations (u2..u19), then final fp32 iteration -> d_out
    uint2* src = uA;
    uint2* dst = uB;
    for (int it = 0; it < N_ITER - 2; it++) {
        k_iter<false><<<PBLK, 256, 0, stream>>>(src, dst, S, desc_i, cnt_p, col_s, dis);
        uint2* t = src; src = dst; dst = t;
    }
    k_iter<true><<<PBLK, 256, 0, stream>>>(src, d_out, S, desc_i, cnt_p, col_s, dis);
}

// Round 4
// 1003.065 us; speedup vs baseline: 1.2718x; 1.2718x over previous
//
#include <hip/hip_runtime.h>
#include <hip/hip_fp16.h>

#define D 128
#define N_ITER 20
#define HBITS 15                  // 32768 nodes per range
#define HWORDS (1 << (HBITS - 1)) // 16384 packed uint16-pair words = 64 KB LDS

// ---------------- mask dtype detection (sampled prefix is sufficient) ----------------
__global__ void k_detect(const unsigned char* __restrict__ m, int nbytes, int* flag) {
    __shared__ int s;
    if (threadIdx.x == 0) s = 0;
    __syncthreads();
    int c = 0;
    for (int i = threadIdx.x; i < nbytes; i += 256)
        if ((i & 3) && m[i]) c++;
    atomicAdd(&s, c);
    __syncthreads();
    if (threadIdx.x == 0) *flag = (s > 0) ? 1 : 0;
}

__global__ void k_mask(const void* __restrict__ mraw, const int* __restrict__ flag,
                       unsigned char* __restrict__ m8, int* __restrict__ nm, int n) {
    int i = blockIdx.x * 256 + threadIdx.x;
    if (i >= n) return;
    unsigned char v;
    if (*flag) {
        v = ((const unsigned char*)mraw)[i] != 0;
    } else {
        v = ((const int*)mraw)[i] != 0;
    }
    m8[i] = v;
    nm[i] = v ? 0 : 1;
}

// ---------------- histogram: range-partitioned, LDS-privatized, packed u16 ----------
__global__ __launch_bounds__(256) void k_hist(const int* __restrict__ keys, int E,
                                              int Bp, int per,
                                              unsigned int* __restrict__ sc) {
    __shared__ unsigned int h[HWORDS];
    int r = blockIdx.x / Bp;
    int b = blockIdx.x - r * Bp;
    for (int i = threadIdx.x; i < HWORDS; i += 256) h[i] = 0;
    __syncthreads();
    int lo = r << HBITS;
    int beg = b * per;
    int end = min(beg + per, E);
    int e = beg + (threadIdx.x << 2);
    for (; e + 3 < end; e += 1024) {
        int4 k4 = *(const int4*)(keys + e);
        int k;
        k = k4.x - lo; if ((unsigned)k < (unsigned)(1 << HBITS)) atomicAdd(&h[k >> 1], 1u << ((k & 1) << 4));
        k = k4.y - lo; if ((unsigned)k < (unsigned)(1 << HBITS)) atomicAdd(&h[k >> 1], 1u << ((k & 1) << 4));
        k = k4.z - lo; if ((unsigned)k < (unsigned)(1 << HBITS)) atomicAdd(&h[k >> 1], 1u << ((k & 1) << 4));
        k = k4.w - lo; if ((unsigned)k < (unsigned)(1 << HBITS)) atomicAdd(&h[k >> 1], 1u << ((k & 1) << 4));
    }
    for (int ee = e; ee < end && ee < e + 4; ee++) {
        int k = keys[ee] - lo;
        if ((unsigned)k < (unsigned)(1 << HBITS)) atomicAdd(&h[k >> 1], 1u << ((k & 1) << 4));
    }
    __syncthreads();
    unsigned int* out = sc + ((size_t)blockIdx.x << (HBITS - 1));
    for (int i = threadIdx.x; i < HWORDS; i += 256) out[i] = h[i];
}

// ---------------- reduce per-block histograms -> dis (MODE 0) or rdeg (MODE 1) ------
template <int MODE>
__global__ void k_red(const unsigned int* __restrict__ sc, int Bp,
                      const unsigned char* __restrict__ m8,
                      float* __restrict__ dis, int* __restrict__ rdeg, int N, int R) {
    int w = blockIdx.x * 256 + threadIdx.x;
    if (w >= (R << (HBITS - 1))) return;
    int r = w >> (HBITS - 1);
    int word = w & (HWORDS - 1);
    int n0 = (r << HBITS) + (word << 1);
    if (n0 >= N) return;
    const unsigned int* p = sc + (((size_t)r * Bp) << (HBITS - 1)) + word;
    unsigned int slo = 0, shi = 0;
    for (int b = 0; b < Bp; b++) {
        unsigned int v = p[(size_t)b << (HBITS - 1)];
        slo += v & 0xffffu;
        shi += v >> 16;
    }
    if (MODE == 0) {
        dis[n0] = slo ? rsqrtf((float)slo) : 0.f;
        if (n0 + 1 < N) dis[n0 + 1] = shi ? rsqrtf((float)shi) : 0.f;
    } else {
        rdeg[n0] = m8[n0] ? 0 : (int)slo;
        if (n0 + 1 < N) rdeg[n0 + 1] = m8[n0 + 1] ? 0 : (int)shi;
    }
}

// ---------------- exclusive scan (generic over input array) ----------------
__global__ void k_scan1(const int* __restrict__ a, int* __restrict__ csum, int n) {
    __shared__ int sh[256];
    int base = blockIdx.x * 2048;
    int t = threadIdx.x;
    int s = 0;
    for (int j = 0; j < 8; j++) {
        int i = base + t * 8 + j;
        if (i < n) s += a[i];
    }
    sh[t] = s;
    __syncthreads();
    for (int o = 128; o > 0; o >>= 1) {
        if (t < o) sh[t] += sh[t + o];
        __syncthreads();
    }
    if (t == 0) csum[blockIdx.x] = sh[0];
}

__global__ void k_scan2(int* __restrict__ csum, int nch, int* __restrict__ out_off, int n) {
    if (threadIdx.x == 0) {
        int acc = 0;
        for (int i = 0; i < nch; i++) { int v = csum[i]; csum[i] = acc; acc += v; }
        out_off[n] = acc;
    }
}

__global__ void k_scan3(const int* __restrict__ a, const int* __restrict__ csum,
                        int* __restrict__ out_off, int n) {
    __shared__ int sh[256];
    int base = blockIdx.x * 2048;
    int t = threadIdx.x;
    int loc[8];
    int s = 0;
    for (int j = 0; j < 8; j++) {
        int i = base + t * 8 + j;
        int v = (i < n) ? a[i] : 0;
        loc[j] = s;
        s += v;
    }
    sh[t] = s;
    __syncthreads();
    for (int o = 1; o < 256; o <<= 1) {
        int v = (t >= o) ? sh[t - o] : 0;
        __syncthreads();
        sh[t] += v;
        __syncthreads();
    }
    int toff = csum[blockIdx.x] + ((t > 0) ? sh[t - 1] : 0);
    for (int j = 0; j < 8; j++) {
        int i = base + t * 8 + j;
        if (i < n) out_off[i] = toff + loc[j];
    }
}

// ---------------- ordered compact: rows_c[cpos[i]] = i for unmasked i ----------------
__global__ void k_fill(const unsigned char* __restrict__ m8, const int* __restrict__ cpos,
                       int* __restrict__ rows_c, int n) {
    int i = blockIdx.x * 256 + threadIdx.x;
    if (i >= n) return;
    if (!m8[i]) rows_c[cpos[i]] = i;
}

// ---------------- scatter: masked cols front / unmasked cols back --------------------
__global__ void k_scatter(const int* __restrict__ row, const int* __restrict__ col, int E,
                          const unsigned char* __restrict__ m8,
                          const int* __restrict__ row_off,
                          int* __restrict__ cur_m, int* __restrict__ cur_u,
                          int* __restrict__ col_s) {
    int e = blockIdx.x * 256 + threadIdx.x;
    if (e >= E) return;
    int r = row[e];
    if (m8[r]) return;
    int c = col[e];
    int p;
    if (m8[c]) p = row_off[r] + atomicAdd(&cur_m[r], 1);
    else       p = row_off[r + 1] - 1 - atomicAdd(&cur_u[r], 1);
    col_s[p] = c;
}

// ---------------- per-row descriptors: one 16B load replaces a dependent chain -------
__global__ void k_desc(const int* __restrict__ rows_c, const int* __restrict__ cnt_p,
                       const int* __restrict__ row_off, const int* __restrict__ cur_m,
                       int4* __restrict__ di, int4* __restrict__ dsx) {
    int i = blockIdx.x * 256 + threadIdx.x;
    if (i >= *cnt_p) return;
    int r = rows_c[i];
    int ro = row_off[r];
    int cm = cur_m[r];
    int ro1 = row_off[r + 1];
    di[i]  = make_int4(r, ro + cm, ro1, 0);   // unmasked-col edge range (per-iteration gather)
    dsx[i] = make_int4(r, ro, ro + cm, 0);    // masked-col edge range (S_fix)
}

// ---------------- init: masked rows of d_out = x ----------------
__global__ void k_init(const float* __restrict__ x, const unsigned char* __restrict__ m8,
                       float* __restrict__ out, int nvec) {
    int i = blockIdx.x * 256 + threadIdx.x;  // float4 index, 32 per node
    if (i >= nvec) return;
    int node = i >> 5;
    if (m8[node]) ((float4*)out)[i] = ((const float4*)x)[i];
}

// ---------------- S_fix[r] = sum over masked cols of dis[c]*x[c]  (fp16 store) -------
// Also writes u1[r] = dis[r]^2 * S_fix[r].
__global__ __launch_bounds__(256) void k_sfix(const float* __restrict__ x,
                                              const float* __restrict__ dis,
                                              const int4* __restrict__ desc,
                                              const int* __restrict__ cnt_p,
                                              const int* __restrict__ col_s,
                                              uint2* __restrict__ S,
                                              uint2* __restrict__ u1) {
    int wgid = (blockIdx.x * 256 + threadIdx.x) >> 6;
    int lane = threadIdx.x & 63;
    int nw = gridDim.x << 2;
    int cn = *cnt_p;

    int s = lane >> 5;     // edge slot 0..1
    int f = lane & 31;     // float4 slot within 512B row
    const float4* xb = (const float4*)x + f;

    for (int wid = wgid; wid < cn; wid += nw) {
        int4 dsc = desc[wid];
        int r   = __builtin_amdgcn_readfirstlane(dsc.x);
        int beg = __builtin_amdgcn_readfirstlane(dsc.y);
        int end = __builtin_amdgcn_readfirstlane(dsc.z);

        float a0 = 0, a1 = 0, a2 = 0, a3 = 0;
        float b0 = 0, b1 = 0, b2 = 0, b3 = 0;
        int e = beg;
        for (; e + 8 <= end; e += 8) {
            int c0 = col_s[e + s],     c1 = col_s[e + 2 + s];
            int c2 = col_s[e + 4 + s], c3 = col_s[e + 6 + s];
            float w0 = dis[c0], w1 = dis[c1], w2 = dis[c2], w3 = dis[c3];
            float4 v0 = xb[(size_t)c0 * 32];
            float4 v1 = xb[(size_t)c1 * 32];
            float4 v2 = xb[(size_t)c2 * 32];
            float4 v3 = xb[(size_t)c3 * 32];
            a0 += w0 * v0.x; a1 += w0 * v0.y; a2 += w0 * v0.z; a3 += w0 * v0.w;
            b0 += w1 * v1.x; b1 += w1 * v1.y; b2 += w1 * v1.z; b3 += w1 * v1.w;
            a0 += w2 * v2.x; a1 += w2 * v2.y; a2 += w2 * v2.z; a3 += w2 * v2.w;
            b0 += w3 * v3.x; b1 += w3 * v3.y; b2 += w3 * v3.z; b3 += w3 * v3.w;
        }
        for (; e + 2 <= end; e += 2) {
            int c = col_s[e + s];
            float w = dis[c];
            float4 v = xb[(size_t)c * 32];
            a0 += w * v.x; a1 += w * v.y; a2 += w * v.z; a3 += w * v.w;
        }
        if (e < end && s == 0) {
            int c = col_s[e];
            float w = dis[c];
            float4 v = xb[(size_t)c * 32];
            a0 += w * v.x; a1 += w * v.y; a2 += w * v.z; a3 += w * v.w;
        }
        a0 += b0; a1 += b1; a2 += b2; a3 += b3;
        a0 += __shfl_xor(a0, 32, 64);
        a1 += __shfl_xor(a1, 32, 64);
        a2 += __shfl_xor(a2, 32, 64);
        a3 += __shfl_xor(a3, 32, 64);
        if (lane < 32) {
            __half2 h0 = __floats2half2_rn(a0, a1);
            __half2 h1 = __floats2half2_rn(a2, a3);
            uint2 o;
            __builtin_memcpy(&o.x, &h0, 4);
            __builtin_memcpy(&o.y, &h1, 4);
            S[(size_t)r * 32 + f] = o;
            float dd = dis[r];
            float ss = dd * dd;
            __half2 g0 = __floats2half2_rn(ss * a0, ss * a1);
            __half2 g1 = __floats2half2_rn(ss * a2, ss * a3);
            uint2 o2;
            __builtin_memcpy(&o2.x, &g0, 4);
            __builtin_memcpy(&o2.y, &g1, 4);
            u1[(size_t)r * 32 + f] = o2;
        }
    }
}

// ---------------- iteration: 16-lane x 16B layout, 4 edges per wave-instruction ------
// u_new[r] = dis^2 * (S_fix[r] + sum u[c]); final: out[r] = dis * (...) fp32.
__device__ __forceinline__ void acc8(const uint4& g,
                                     float& x0, float& x1, float& x2, float& x3,
                                     float& x4, float& x5, float& x6, float& x7) {
    __half2 h; float2 v;
    __builtin_memcpy(&h, &g.x, 4); v = __half22float2(h); x0 += v.x; x1 += v.y;
    __builtin_memcpy(&h, &g.y, 4); v = __half22float2(h); x2 += v.x; x3 += v.y;
    __builtin_memcpy(&h, &g.z, 4); v = __half22float2(h); x4 += v.x; x5 += v.y;
    __builtin_memcpy(&h, &g.w, 4); v = __half22float2(h); x6 += v.x; x7 += v.y;
}

template <bool FINAL>
__global__ __launch_bounds__(256) void k_iter(const uint4* __restrict__ src,
                                              void* __restrict__ dst,
                                              const uint4* __restrict__ S,
                                              const int4* __restrict__ desc,
                                              const int* __restrict__ cnt_p,
                                              const int* __restrict__ col_s,
                                              const float* __restrict__ dis) {
    int wgid = (blockIdx.x * 256 + threadIdx.x) >> 6;
    int lane = threadIdx.x & 63;
    int nw = gridDim.x << 2;
    int cn = *cnt_p;

    int s = lane >> 4;     // edge slot 0..3
    int f = lane & 15;     // uint4 (half8) slot, row stride 16
    const uint4* cb = src + f;
    const uint4* Sb = S + f;

    for (int wid = wgid; wid < cn; wid += nw) {
        int4 dsc = desc[wid];
        int r   = __builtin_amdgcn_readfirstlane(dsc.x);
        int beg = __builtin_amdgcn_readfirstlane(dsc.y);
        int end = __builtin_amdgcn_readfirstlane(dsc.z);

        float a0 = 0, a1 = 0, a2 = 0, a3 = 0, a4 = 0, a5 = 0, a6 = 0, a7 = 0;
        float b0 = 0, b1 = 0, b2 = 0, b3 = 0, b4 = 0, b5 = 0, b6 = 0, b7 = 0;
        if (s == 0) {
            uint4 sv = Sb[(size_t)r * 16];
            acc8(sv, a0, a1, a2, a3, a4, a5, a6, a7);
        }

        int e = beg;
        for (; e + 16 <= end; e += 16) {
            int c0 = col_s[e + s];
            int c1 = col_s[e + 4 + s];
            int c2 = col_s[e + 8 + s];
            int c3 = col_s[e + 12 + s];
            uint4 g0 = cb[(size_t)c0 * 16];
            uint4 g1 = cb[(size_t)c1 * 16];
            uint4 g2 = cb[(size_t)c2 * 16];
            uint4 g3 = cb[(size_t)c3 * 16];
            acc8(g0, a0, a1, a2, a3, a4, a5, a6, a7);
            acc8(g1, b0, b1, b2, b3, b4, b5, b6, b7);
            acc8(g2, a0, a1, a2, a3, a4, a5, a6, a7);
            acc8(g3, b0, b1, b2, b3, b4, b5, b6, b7);
        }
        for (; e + 4 <= end; e += 4) {
            int c = col_s[e + s];
            uint4 g = cb[(size_t)c * 16];
            acc8(g, a0, a1, a2, a3, a4, a5, a6, a7);
        }
        int rem = end - e;
        if (s < rem) {
            int c = col_s[e + s];
            uint4 g = cb[(size_t)c * 16];
            acc8(g, a0, a1, a2, a3, a4, a5, a6, a7);
        }
        a0 += b0; a1 += b1; a2 += b2; a3 += b3;
        a4 += b4; a5 += b5; a6 += b6; a7 += b7;
        a0 += __shfl_xor(a0, 16, 64); a0 += __shfl_xor(a0, 32, 64);
        a1 += __shfl_xor(a1, 16, 64); a1 += __shfl_xor(a1, 32, 64);
        a2 += __shfl_xor(a2, 16, 64); a2 += __shfl_xor(a2, 32, 64);
        a3 += __shfl_xor(a3, 16, 64); a3 += __shfl_xor(a3, 32, 64);
        a4 += __shfl_xor(a4, 16, 64); a4 += __shfl_xor(a4, 32, 64);
        a5 += __shfl_xor(a5, 16, 64); a5 += __shfl_xor(a5, 32, 64);
        a6 += __shfl_xor(a6, 16, 64); a6 += __shfl_xor(a6, 32, 64);
        a7 += __shfl_xor(a7, 16, 64); a7 += __shfl_xor(a7, 32, 64);

        if (lane < 16) {
            float d = dis[r];
            if (FINAL) {
                float4* o = (float4*)dst + (size_t)r * 32 + f * 2;
                o[0] = make_float4(d * a0, d * a1, d * a2, d * a3);
                o[1] = make_float4(d * a4, d * a5, d * a6, d * a7);
            } else {
                float ss = d * d;
                __half2 h0 = __floats2half2_rn(ss * a0, ss * a1);
                __half2 h1 = __floats2half2_rn(ss * a2, ss * a3);
                __half2 h2 = __floats2half2_rn(ss * a4, ss * a5);
                __half2 h3 = __floats2half2_rn(ss * a6, ss * a7);
                uint4 o;
                __builtin_memcpy(&o.x, &h0, 4);
                __builtin_memcpy(&o.y, &h1, 4);
                __builtin_memcpy(&o.z, &h2, 4);
                __builtin_memcpy(&o.w, &h3, 4);
                ((uint4*)dst)[(size_t)r * 16 + f] = o;
            }
        }
    }
}

extern "C" void kernel_launch(void* const* d_in, const int* in_sizes, int n_in,
                              void* d_out, int out_size, void* d_ws, size_t ws_size,
                              hipStream_t stream) {
    const float* x = (const float*)d_in[0];
    const int* ei = (const int*)d_in[1];
    const void* mraw = d_in[2];

    const int N = in_sizes[0] / D;     // 100000
    const int E = in_sizes[1] / 2;     // 3200000
    const int* row = ei;
    const int* col = ei + E;

    char* ws = (char*)d_ws;
    size_t off = 0;
    uint2* uA = (uint2*)(ws + off);         off += (size_t)N * D * 2;   // fp16 u buffers
    uint2* uB = (uint2*)(ws + off);         off += (size_t)N * D * 2;
    uint2* S  = (uint2*)(ws + off);         off += (size_t)N * D * 2;   // fp16 S_fix
    int* col_s = (int*)(ws + off);          off += (size_t)E * 4;       // CSR cols (filtered, split)
    int* row_off = (int*)(ws + off);        off += (size_t)(N + 1) * 4;
    int* zblock = (int*)(ws + off);         off += (size_t)(2 * N) * 4; // cur_m|cur_u (memset)
    int* cur_m = zblock;
    int* cur_u = zblock + N;
    int* rdeg = (int*)(ws + off);           off += (size_t)N * 4;
    float* dis = (float*)(ws + off);        off += (size_t)N * 4;
    int* rows_c = (int*)(ws + off);         off += (size_t)N * 4;
    int* nm = (int*)(ws + off);             off += (size_t)N * 4;
    int* cpos = (int*)(ws + off);           off += (size_t)(N + 1) * 4;
    unsigned char* m8 = (unsigned char*)(ws + off); off += (size_t)N;
    off = (off + 255) & ~(size_t)255;
    int* csum = (int*)(ws + off);           off += 256 * 4;
    int* csum2 = (int*)(ws + off);          off += 256 * 4;
    int* flag = (int*)(ws + off);           off += 4;
    off = (off + 255) & ~(size_t)255;
    int4* desc_i = (int4*)(ws + off);       off += (size_t)N * 16;
    int4* desc_s = (int4*)(ws + off);       off += (size_t)N * 16;

    const int* cnt_p = cpos + N;   // total unmasked count, written by scan

    // histogram scratch: aliases uA+uB (written only later by k_sfix / k_iter)
    unsigned int* sc = (unsigned int*)ws;

    (void)hipMemsetAsync(zblock, 0, (size_t)(2 * N) * 4, stream);

    int nb = N < 16384 ? N : 16384;
    k_detect<<<1, 256, 0, stream>>>((const unsigned char*)mraw, nb, flag);
    k_mask<<<(N + 255) / 256, 256, 0, stream>>>(mraw, flag, m8, nm, N);

    // degree histograms: col -> dis, row -> rdeg (mask applied at reduce)
    const int R = (N + (1 << HBITS) - 1) >> HBITS;   // 4 ranges of 32768
    const int Bp = 128;                              // slice <= 25008 < 65536
    int per = ((E + Bp - 1) / Bp + 15) & ~15;
    int rwords = (R << (HBITS - 1));
    k_hist<<<R * Bp, 256, 0, stream>>>(col, E, Bp, per, sc);
    k_red<0><<<(rwords + 255) / 256, 256, 0, stream>>>(sc, Bp, m8, dis, rdeg, N, R);
    k_hist<<<R * Bp, 256, 0, stream>>>(row, E, Bp, per, sc);
    k_red<1><<<(rwords + 255) / 256, 256, 0, stream>>>(sc, Bp, m8, dis, rdeg, N, R);

    int nch = (N + 2047) / 2048;
    // scan rdeg -> row_off
    k_scan1<<<nch, 256, 0, stream>>>(rdeg, csum, N);
    k_scan2<<<1, 64, 0, stream>>>(csum, nch, row_off, N);
    k_scan3<<<nch, 256, 0, stream>>>(rdeg, csum, row_off, N);
    // scan !mask -> cpos (ordered compaction positions), cpos[N] = cnt
    k_scan1<<<nch, 256, 0, stream>>>(nm, csum2, N);
    k_scan2<<<1, 64, 0, stream>>>(csum2, nch, cpos, N);
    k_scan3<<<nch, 256, 0, stream>>>(nm, csum2, cpos, N);
    k_fill<<<(N + 255) / 256, 256, 0, stream>>>(m8, cpos, rows_c, N);

    k_scatter<<<(E + 255) / 256, 256, 0, stream>>>(row, col, E, m8, row_off, cur_m, cur_u, col_s);
    k_desc<<<(N + 255) / 256, 256, 0, stream>>>(rows_c, cnt_p, row_off, cur_m, desc_i, desc_s);

    int nvec = N * (D / 4);
    k_init<<<(nvec + 255) / 256, 256, 0, stream>>>(x, m8, (float*)d_out, nvec);

    const int PBLK = 2048;   // persistent grid: 8192 waves, grid-stride over compact rows
    k_sfix<<<PBLK, 256, 0, stream>>>(x, dis, desc_s, cnt_p, col_s, S, uA);

    // u1 in uA; 18 fp16 gather iterations (u2..u19), then final fp32 iteration -> d_out
    uint4* src = (uint4*)uA;
    uint4* dst = (uint4*)uB;
    const uint4* S4 = (const uint4*)S;
    for (int it = 0; it < N_ITER - 2; it++) {
        k_iter<false><<<PBLK, 256, 0, stream>>>(src, dst, S4, desc_i, cnt_p, col_s, dis);
        uint4* t = src; src = dst; dst = t;
    }
    k_iter<true><<<PBLK, 256, 0, stream>>>(src, d_out, S4, desc_i, cnt_p, col_s, dis);
}